// Round 1
// baseline (1806.232 us; speedup 1.0000x reference)
//
#include <hip/hip_runtime.h>

// ---------------------------------------------------------------------------
// FCOS head on MI355X: bf16 MFMA implicit-GEMM 3x3 convs (m97 structure).
// Layouts:
//   activations: padded NHWC bf16, [B][H+2][W+2][256], zero borders
//   stem weights: [s][tap][co][ci] bf16 (B^T, row-contiguous in ci)
//   pred weights: [tap][co][ci] bf16 (cls: 80 rows; box+ctr: 16 rows, 5 valid)
// GEMM per conv: M = B*H*W, N = co, K = 9*256 (chunks of 64, tap-aligned)
// ---------------------------------------------------------------------------

typedef __bf16 bf16;
typedef __attribute__((ext_vector_type(8))) __bf16 bf16x8;
typedef __attribute__((ext_vector_type(4))) float f32x4;

typedef unsigned int uint32_as1 __attribute__((address_space(1)));
typedef unsigned int uint32_as3 __attribute__((address_space(3)));

// async global->LDS, 16B per lane. LDS dest is wave-uniform base + lane*16,
// so callers MUST pass lds ptr = base + tid*8 bf16 elems (lane-contiguous).
__device__ __forceinline__ void gl_lds16(const bf16* g, bf16* l) {
    __builtin_amdgcn_global_load_lds(
        (const uint32_as1*)(unsigned long long)g,
        (uint32_as3*)(unsigned int)(unsigned long long)l,
        16, 0, 0);
}

// ---------------------------------------------------------------------------
// Stem conv: dual-path (z=0 cls, z=1 box). BMxBN tile, BK=64, 4 waves (2x2),
// each wave (BM/2)x(BN/2) via 16x16x32 bf16 MFMA. Bias+ReLU+bf16 epilogue
// into padded NHWC output.
// ---------------------------------------------------------------------------
template <int BM, int BN>
__global__ __launch_bounds__(256) void stem_conv_kernel(
    const bf16* __restrict__ Ac, const bf16* __restrict__ Ab,
    bf16* __restrict__ Oc, bf16* __restrict__ Ob,
    const bf16* __restrict__ Wc, const bf16* __restrict__ Wb,
    const float* __restrict__ bc, const float* __restrict__ bb,
    int H, int lw, int lhw)
{
    constexpr int FM = BM / 32;   // A frags per wave == A staging slots/thread
    constexpr int FN = BN / 32;

    const bf16* A; bf16* O; const bf16* BT; const float* bias;
    if (blockIdx.z == 0) { A = Ac; O = Oc; BT = Wc; bias = bc; }
    else                 { A = Ab; O = Ob; BT = Wb; bias = bb; }

    const int W   = 1 << lw;
    const int Wp  = W + 2;
    const int HW  = 1 << lhw;
    const int tid = threadIdx.x;
    const int m_base = blockIdx.x * BM;
    const int n0     = blockIdx.y * BN;
    const int b   = m_base >> lhw;              // tile never crosses images
    const int y0  = (m_base & (HW - 1)) >> lw;  // tile starts at row boundary
    const int ibase = b * (H + 2) * Wp * 256;

    __shared__ __align__(16) bf16 Als[BM * 64];
    __shared__ __align__(16) bf16 Bls[BN * 64];

    // staging addresses: slot i covers tile row (i*32 + tid/8), 8B-chunk tid%8
    const int ch8   = (tid & 7) << 3;
    const int rbase = tid >> 3;
    int ag[FM], bg[FN];
#pragma unroll
    for (int i = 0; i < FM; ++i) {
        int row = i * 32 + rbase;
        int y = y0 + (row >> lw);
        int x = row & (W - 1);
        ag[i] = ibase + (y * Wp + x) * 256 + ch8;  // tap adds (dy*Wp+dx)*256
    }
#pragma unroll
    for (int i = 0; i < FN; ++i)
        bg[i] = (n0 + i * 32 + rbase) * 256 + ch8; // tap adds t*65536

    f32x4 acc[FM][FN];
#pragma unroll
    for (int i = 0; i < FM; ++i)
#pragma unroll
        for (int j = 0; j < FN; ++j)
            acc[i][j] = (f32x4)(0.0f);

    const int lane = tid & 63;
    const int wv   = tid >> 6;
    const int wm   = (wv & 1) * (BM / 2);
    const int wn   = (wv >> 1) * (BN / 2);
    const int l16  = lane & 15;
    const int quad = lane >> 4;
    // fragment LDS offsets (A-operand: [m=lane&15][k=quad*8+j], verified m89/m120)
    const int a_off = (wm + l16) * 64 + quad * 8;
    const int b_off = (wn + l16) * 64 + quad * 8;
    bf16* lA = Als + tid * 8;
    bf16* lB = Bls + tid * 8;

    for (int kc = 0; kc < 36; ++kc) {   // K = 9 taps * 4 chunks of 64
        const int t  = kc >> 2;
        const int dy = t / 3;
        const int dx = t - dy * 3;
        const int c0 = (kc & 3) << 6;
        const int aoff = (dy * Wp + dx) * 256 + c0;
        const int boff = t * 65536 + c0;
#pragma unroll
        for (int i = 0; i < FM; ++i)
            gl_lds16(A + ag[i] + aoff, lA + i * 2048);
#pragma unroll
        for (int i = 0; i < FN; ++i)
            gl_lds16(BT + bg[i] + boff, lB + i * 2048);
        __syncthreads();
#pragma unroll
        for (int ks = 0; ks < 2; ++ks) {
            bf16x8 af[FM], bfv[FN];
#pragma unroll
            for (int i = 0; i < FM; ++i)
                af[i] = *(const bf16x8*)(Als + a_off + i * (16 * 64) + ks * 32);
#pragma unroll
            for (int j = 0; j < FN; ++j)
                bfv[j] = *(const bf16x8*)(Bls + b_off + j * (16 * 64) + ks * 32);
#pragma unroll
            for (int i = 0; i < FM; ++i)
#pragma unroll
                for (int j = 0; j < FN; ++j)
                    acc[i][j] = __builtin_amdgcn_mfma_f32_16x16x32_bf16(
                        af[i], bfv[j], acc[i][j], 0, 0, 0);
        }
        __syncthreads();
    }

    // epilogue: C/D layout col=lane&15 (n), row=quad*4+reg (m)  [m89/m91]
    float bv[FN];
#pragma unroll
    for (int j = 0; j < FN; ++j) bv[j] = bias[n0 + wn + j * 16 + l16];
#pragma unroll
    for (int i = 0; i < FM; ++i) {
#pragma unroll
        for (int r = 0; r < 4; ++r) {
            const int ml = wm + i * 16 + quad * 4 + r;
            const int y  = y0 + (ml >> lw);
            const int x  = ml & (W - 1);
            const int ob = ibase + ((y + 1) * Wp + (x + 1)) * 256 + n0 + wn;
#pragma unroll
            for (int j = 0; j < FN; ++j) {
                float v = acc[i][j][r] + bv[j];
                v = v > 0.0f ? v : 0.0f;
                O[ob + j * 16 + l16] = (bf16)v;
            }
        }
    }
}

// ---------------------------------------------------------------------------
// Prediction conv: M-tile 128, N = NB*16 (cls: NB=5/80 valid; boxctr: NB=1/5
// valid). No ReLU; writes fp32 straight into d_out (B,5376,85) layout at J0.
// ---------------------------------------------------------------------------
template <int NB, int NVALID, int J0>
__global__ __launch_bounds__(256) void pred_conv_kernel(
    const bf16* __restrict__ A, const bf16* __restrict__ BT,
    const float* __restrict__ bias, float* __restrict__ out,
    int H, int lw, int lhw, int off_l)
{
    const int W   = 1 << lw;
    const int Wp  = W + 2;
    const int HW  = 1 << lhw;
    const int tid = threadIdx.x;
    const int m_base = blockIdx.x * 128;
    const int b   = m_base >> lhw;
    const int mi  = m_base & (HW - 1);
    const int y0  = mi >> lw;
    const int ibase = b * (H + 2) * Wp * 256;

    __shared__ __align__(16) bf16 Als[128 * 64];
    __shared__ __align__(16) bf16 Bls[NB * 16 * 64];

    const int ch8   = (tid & 7) << 3;
    const int rbase = tid >> 3;
    int ag[4];
#pragma unroll
    for (int i = 0; i < 4; ++i) {
        int row = i * 32 + rbase;
        int y = y0 + (row >> lw);
        int x = row & (W - 1);
        ag[i] = ibase + (y * Wp + x) * 256 + ch8;
    }

    f32x4 acc[2][NB];
#pragma unroll
    for (int i = 0; i < 2; ++i)
#pragma unroll
        for (int j = 0; j < NB; ++j)
            acc[i][j] = (f32x4)(0.0f);

    const int lane = tid & 63;
    const int wv   = tid >> 6;      // wave handles m rows [wv*32, wv*32+32)
    const int l16  = lane & 15;
    const int quad = lane >> 4;
    const int a_off = (wv * 32 + l16) * 64 + quad * 8;
    const int b_off = l16 * 64 + quad * 8;
    bf16* lA = Als + tid * 8;

    for (int kc = 0; kc < 36; ++kc) {
        const int t  = kc >> 2;
        const int dy = t / 3;
        const int dx = t - dy * 3;
        const int c0 = (kc & 3) << 6;
        const int aoff = (dy * Wp + dx) * 256 + c0;
#pragma unroll
        for (int i = 0; i < 4; ++i)
            gl_lds16(A + ag[i] + aoff, lA + i * 2048);
        // B tile via plain loads (weights tiny, L2-resident)
        for (int s = tid; s < NB * 128; s += 256) {
            int row = s >> 3;
            int ch  = (s & 7) << 3;
            *(uint4*)(Bls + row * 64 + ch) =
                *(const uint4*)(BT + (t * (NB * 16) + row) * 256 + c0 + ch);
        }
        __syncthreads();
#pragma unroll
        for (int ks = 0; ks < 2; ++ks) {
            bf16x8 af[2], bfv[NB];
#pragma unroll
            for (int i = 0; i < 2; ++i)
                af[i] = *(const bf16x8*)(Als + a_off + i * (16 * 64) + ks * 32);
#pragma unroll
            for (int j = 0; j < NB; ++j)
                bfv[j] = *(const bf16x8*)(Bls + b_off + j * (16 * 64) + ks * 32);
#pragma unroll
            for (int i = 0; i < 2; ++i)
#pragma unroll
                for (int j = 0; j < NB; ++j)
                    acc[i][j] = __builtin_amdgcn_mfma_f32_16x16x32_bf16(
                        af[i], bfv[j], acc[i][j], 0, 0, 0);
        }
        __syncthreads();
    }

#pragma unroll
    for (int i = 0; i < 2; ++i) {
#pragma unroll
        for (int r = 0; r < 4; ++r) {
            const int ml  = wv * 32 + i * 16 + quad * 4 + r;
            const int pos = mi + ml;
            const int ob  = (b * 5376 + off_l + pos) * 85 + J0;
#pragma unroll
            for (int j = 0; j < NB; ++j) {
                const int n = j * 16 + l16;
                if (NVALID == NB * 16 || n < NVALID)
                    out[ob + n] = acc[i][j][r] + bias[n];
            }
        }
    }
}

// ---------------------------------------------------------------------------
// Layout transforms
// ---------------------------------------------------------------------------

// fp32 NCHW -> padded NHWC bf16 (interior only; borders pre-zeroed)
__global__ void cast_pad_kernel(const float* __restrict__ in, bf16* __restrict__ out,
                                int H, int lw)
{
    const int c  = threadIdx.x;
    const int hw = blockIdx.x;
    const int b  = blockIdx.y;
    const int W  = 1 << lw;
    const int y  = hw >> lw;
    const int x  = hw & (W - 1);
    float v = in[((b * 256 + c) * H + y) * W + x];
    out[((b * (H + 2) + y + 1) * (W + 2) + (x + 1)) * 256 + c] = (bf16)v;
}

// stem weights (S,co,ci,3,3) fp32 -> [s][t][co][ci] bf16
__global__ void prepack_stem_kernel(const float* __restrict__ w, bf16* __restrict__ o)
{
    const int ci = threadIdx.x;
    const int g  = blockIdx.x;          // (s*9+t)*256 + co, g < 9216
    const int co = g & 255;
    const int st = g >> 8;
    const int s  = st / 9;
    const int t  = st - s * 9;
    o[(size_t)g * 256 + ci] = (bf16)w[(((s * 256 + co) * 256 + ci) * 9) + t];
}

// pred weights -> [t][80][256] (cls) and [t][16][256] (box 0..3, ctr 4, pad 0)
__global__ void prepack_pred_kernel(const float* __restrict__ wc,
                                    const float* __restrict__ wb,
                                    const float* __restrict__ wr,
                                    const float* __restrict__ bb,
                                    const float* __restrict__ br,
                                    bf16* __restrict__ oc, bf16* __restrict__ obc,
                                    float* __restrict__ obias)
{
    const int ci = threadIdx.x;
    const int g  = blockIdx.x;          // 0 .. 9*85-1
    const int t  = g / 85;
    const int co = g - t * 85;
    if (co < 80) {
        oc[((t * 80 + co) * 256) + ci] = (bf16)wc[((co * 256 + ci) * 9) + t];
    } else {
        const int c2 = co - 80;         // 0..4
        float v = (c2 < 4) ? wb[((c2 * 256 + ci) * 9) + t] : wr[(ci * 9) + t];
        obc[((t * 16 + c2) * 256) + ci] = (bf16)v;
    }
    if (g == 0 && ci < 16)
        obias[ci] = (ci < 4) ? bb[ci] : (ci == 4 ? br[0] : 0.0f);
}

// ---------------------------------------------------------------------------
extern "C" void kernel_launch(void* const* d_in, const int* in_sizes, int n_in,
                              void* d_out, int out_size, void* d_ws, size_t ws_size,
                              hipStream_t stream)
{
    (void)in_sizes; (void)n_in; (void)out_size;
    const float* feat[3] = {(const float*)d_in[0], (const float*)d_in[1],
                            (const float*)d_in[2]};
    const float* scw = (const float*)d_in[3];
    const float* scb = (const float*)d_in[4];
    const float* sbw = (const float*)d_in[5];
    const float* sbb = (const float*)d_in[6];
    const float* pcw = (const float*)d_in[7];
    const float* pcb = (const float*)d_in[8];
    const float* pbw = (const float*)d_in[9];
    const float* pbb = (const float*)d_in[10];
    const float* prw = (const float*)d_in[11];
    const float* prb = (const float*)d_in[12];
    float* out = (float*)d_out;

    char* ws = (char*)d_ws;
    const size_t BUF3 = (size_t)16 * 66 * 66 * 256 * 2;  // 35,684,352 B
    size_t off = 5 * BUF3;                                // 5 act buffers (p3-sized)
    bf16*  wbTc = (bf16*)(ws + off); off += (size_t)4 * 9 * 256 * 256 * 2;
    bf16*  wbTb = (bf16*)(ws + off); off += (size_t)4 * 9 * 256 * 256 * 2;
    bf16*  pcT  = (bf16*)(ws + off); off += (size_t)9 * 80 * 256 * 2;
    bf16*  pbcT = (bf16*)(ws + off); off += (size_t)9 * 16 * 256 * 2;
    float* pbcB = (float*)(ws + off); off += 256;
    if (ws_size < off) return;  // ~188.3 MB required

    // zero everything once: act borders, pbcT pad rows, bias pad
    hipMemsetAsync(d_ws, 0, off, stream);

    prepack_stem_kernel<<<dim3(9216), 256, 0, stream>>>(scw, wbTc);
    prepack_stem_kernel<<<dim3(9216), 256, 0, stream>>>(sbw, wbTb);
    prepack_pred_kernel<<<dim3(9 * 85), 256, 0, stream>>>(pcw, pbw, prw, pbb, prb,
                                                          pcT, pbcT, pbcB);

    const int Hs[3]   = {64, 32, 16};
    const int lws[3]  = {6, 5, 4};
    const int lhws[3] = {12, 10, 8};
    const int offl[3] = {0, 4096, 5120};

    for (int l = 0; l < 3; ++l) {
        const int H = Hs[l], lw = lws[l], lhw = lhws[l];
        const size_t buf = (size_t)16 * (H + 2) * (H + 2) * 256 * 2;
        bf16* X0  = (bf16*)(ws);
        bf16* Xc1 = (bf16*)(ws + buf);
        bf16* Xc2 = (bf16*)(ws + 2 * buf);
        bf16* Xb1 = (bf16*)(ws + 3 * buf);
        bf16* Xb2 = (bf16*)(ws + 4 * buf);
        if (l > 0)  // re-zero borders for the smaller geometry
            hipMemsetAsync(ws, 0, 5 * buf, stream);

        cast_pad_kernel<<<dim3(H * H, 16), 256, 0, stream>>>(feat[l], X0, H, lw);

        const int M = 16 << lhw;
        const bf16* inC = X0;
        const bf16* inB = X0;
        for (int s = 0; s < 4; ++s) {
            bf16* oc = (s & 1) ? Xc2 : Xc1;
            bf16* ob = (s & 1) ? Xb2 : Xb1;
            const bf16* wc = wbTc + (size_t)s * 589824;
            const bf16* wb = wbTb + (size_t)s * 589824;
            if (l < 2) {
                stem_conv_kernel<128, 128><<<dim3(M / 128, 2, 2), 256, 0, stream>>>(
                    inC, inB, oc, ob, wc, wb, scb + s * 256, sbb + s * 256,
                    H, lw, lhw);
            } else {  // p5: small M -> 64x64 tiles for 512 blocks
                stem_conv_kernel<64, 64><<<dim3(M / 64, 4, 2), 256, 0, stream>>>(
                    inC, inB, oc, ob, wc, wb, scb + s * 256, sbb + s * 256,
                    H, lw, lhw);
            }
            inC = oc;
            inB = ob;
        }
        pred_conv_kernel<5, 80, 0><<<dim3(M / 128), 256, 0, stream>>>(
            inC, pcT, pcb, out, H, lw, lhw, offl[l]);
        pred_conv_kernel<1, 5, 80><<<dim3(M / 128), 256, 0, stream>>>(
            inB, pbcT, pbcB, out, H, lw, lhw, offl[l]);
    }
}

// Round 2
// 1572.101 us; speedup vs baseline: 1.1489x; 1.1489x over previous
//
#include <hip/hip_runtime.h>

// ---------------------------------------------------------------------------
// FCOS head on MI355X: bf16 MFMA implicit-GEMM 3x3 convs (m97 structure).
// Layouts:
//   activations: padded NHWC bf16, [B][H+2][W+2][256], zero borders
//   stem weights: [s][tap][co][ci] bf16 (B^T, row-contiguous in ci)
//   pred weights: [tap][co][ci] bf16 (cls: 80 rows; box+ctr: 16 rows, 5 valid)
// GEMM per conv: M = B*H*W, N = co, K = 9*256 (chunks of 64, tap-aligned)
//
// LDS layout is XOR-swizzled: LDS row r, 16B-chunk c holds GLOBAL chunk
// c ^ (r&7). Implemented by permuting the global source per lane (staging
// stays lane-contiguous in LDS as global_load_lds requires; the permutation
// stays within one 128B line so global coalescing is preserved). This kills
// the 16-way bank conflict on ds_read_b128 fragment reads (was 5.66e7
// conflict cycles/dispatch = ~36% of CU-cycles).
// ---------------------------------------------------------------------------

typedef __bf16 bf16;
typedef __attribute__((ext_vector_type(8))) __bf16 bf16x8;
typedef __attribute__((ext_vector_type(4))) float f32x4;

typedef unsigned int uint32_as1 __attribute__((address_space(1)));
typedef unsigned int uint32_as3 __attribute__((address_space(3)));

// async global->LDS, 16B per lane. LDS dest is wave-uniform base + lane*16,
// so callers MUST pass lds ptr = base + tid*8 bf16 elems (lane-contiguous).
__device__ __forceinline__ void gl_lds16(const bf16* g, bf16* l) {
    __builtin_amdgcn_global_load_lds(
        (const uint32_as1*)(unsigned long long)g,
        (uint32_as3*)(unsigned int)(unsigned long long)l,
        16, 0, 0);
}

// ---------------------------------------------------------------------------
// Stem conv: dual-path (z=0 cls, z=1 box). BMxBN tile, BK=64, 4 waves (2x2),
// each wave (BM/2)x(BN/2) via 16x16x32 bf16 MFMA. Bias+ReLU+bf16 epilogue
// into padded NHWC output.
// ---------------------------------------------------------------------------
template <int BM, int BN>
__global__ __launch_bounds__(256) void stem_conv_kernel(
    const bf16* __restrict__ Ac, const bf16* __restrict__ Ab,
    bf16* __restrict__ Oc, bf16* __restrict__ Ob,
    const bf16* __restrict__ Wc, const bf16* __restrict__ Wb,
    const float* __restrict__ bc, const float* __restrict__ bb,
    int H, int lw, int lhw)
{
    constexpr int FM = BM / 32;   // A frags per wave == A staging slots/thread
    constexpr int FN = BN / 32;

    const bf16* A; bf16* O; const bf16* BT; const float* bias;
    if (blockIdx.z == 0) { A = Ac; O = Oc; BT = Wc; bias = bc; }
    else                 { A = Ab; O = Ob; BT = Wb; bias = bb; }

    const int W   = 1 << lw;
    const int Wp  = W + 2;
    const int HW  = 1 << lhw;
    const int tid = threadIdx.x;
    const int m_base = blockIdx.x * BM;
    const int n0     = blockIdx.y * BN;
    const int b   = m_base >> lhw;              // tile never crosses images
    const int y0  = (m_base & (HW - 1)) >> lw;  // tile starts at row boundary
    const int ibase = b * (H + 2) * Wp * 256;

    __shared__ __align__(16) bf16 Als[BM * 64];
    __shared__ __align__(16) bf16 Bls[BN * 64];

    // staging: lane tid -> LDS row tid/8, chunk tid%8 (lane-contiguous).
    // Global source chunk = (tid%8) ^ (row%8)  -> XOR-swizzled LDS layout.
    const int ch8   = (((tid & 7) ^ ((tid >> 3) & 7)) << 3);
    const int rbase = tid >> 3;
    int ag[FM], bg[FN];
#pragma unroll
    for (int i = 0; i < FM; ++i) {
        int row = i * 32 + rbase;
        int y = y0 + (row >> lw);
        int x = row & (W - 1);
        ag[i] = ibase + (y * Wp + x) * 256 + ch8;  // tap adds (dy*Wp+dx)*256
    }
#pragma unroll
    for (int i = 0; i < FN; ++i)
        bg[i] = (n0 + i * 32 + rbase) * 256 + ch8; // tap adds t*65536

    f32x4 acc[FM][FN];
#pragma unroll
    for (int i = 0; i < FM; ++i)
#pragma unroll
        for (int j = 0; j < FN; ++j)
            acc[i][j] = (f32x4)(0.0f);

    const int lane = tid & 63;
    const int wv   = tid >> 6;
    const int wm   = (wv & 1) * (BM / 2);
    const int wn   = (wv >> 1) * (BN / 2);
    const int l16  = lane & 15;
    const int quad = lane >> 4;
    const int xsw  = l16 & 7;           // row-dependent chunk swizzle
    // fragment LDS row bases (A-operand: [m=lane&15][k=quad*8+j], m89/m120)
    const int aRow = (wm + l16) * 64;
    const int bRow = (wn + l16) * 64;
    bf16* lA = Als + tid * 8;
    bf16* lB = Bls + tid * 8;

    for (int kc = 0; kc < 36; ++kc) {   // K = 9 taps * 4 chunks of 64
        const int t  = kc >> 2;
        const int dy = t / 3;
        const int dx = t - dy * 3;
        const int c0 = (kc & 3) << 6;
        const int aoff = (dy * Wp + dx) * 256 + c0;
        const int boff = t * 65536 + c0;
#pragma unroll
        for (int i = 0; i < FM; ++i)
            gl_lds16(A + ag[i] + aoff, lA + i * 2048);
#pragma unroll
        for (int i = 0; i < FN; ++i)
            gl_lds16(BT + bg[i] + boff, lB + i * 2048);
        __syncthreads();
#pragma unroll
        for (int ks = 0; ks < 2; ++ks) {
            const int cO = (((quad + ks * 4) ^ xsw) << 3);  // swizzled chunk
            bf16x8 af[FM], bfv[FN];
#pragma unroll
            for (int i = 0; i < FM; ++i)
                af[i] = *(const bf16x8*)(Als + aRow + i * (16 * 64) + cO);
#pragma unroll
            for (int j = 0; j < FN; ++j)
                bfv[j] = *(const bf16x8*)(Bls + bRow + j * (16 * 64) + cO);
#pragma unroll
            for (int i = 0; i < FM; ++i)
#pragma unroll
                for (int j = 0; j < FN; ++j)
                    acc[i][j] = __builtin_amdgcn_mfma_f32_16x16x32_bf16(
                        af[i], bfv[j], acc[i][j], 0, 0, 0);
        }
        __syncthreads();
    }

    // epilogue: C/D layout col=lane&15 (n), row=quad*4+reg (m)  [m89/m91]
    float bv[FN];
#pragma unroll
    for (int j = 0; j < FN; ++j) bv[j] = bias[n0 + wn + j * 16 + l16];
#pragma unroll
    for (int i = 0; i < FM; ++i) {
#pragma unroll
        for (int r = 0; r < 4; ++r) {
            const int ml = wm + i * 16 + quad * 4 + r;
            const int y  = y0 + (ml >> lw);
            const int x  = ml & (W - 1);
            const int ob = ibase + ((y + 1) * Wp + (x + 1)) * 256 + n0 + wn;
#pragma unroll
            for (int j = 0; j < FN; ++j) {
                float v = acc[i][j][r] + bv[j];
                v = v > 0.0f ? v : 0.0f;
                O[ob + j * 16 + l16] = (bf16)v;
            }
        }
    }
}

// ---------------------------------------------------------------------------
// Prediction conv: M-tile 128, N = NB*16 (cls: NB=5/80 valid; boxctr: NB=1/5
// valid). No ReLU; writes fp32 straight into d_out (B,5376,85) layout at J0.
// ---------------------------------------------------------------------------
template <int NB, int NVALID, int J0>
__global__ __launch_bounds__(256) void pred_conv_kernel(
    const bf16* __restrict__ A, const bf16* __restrict__ BT,
    const float* __restrict__ bias, float* __restrict__ out,
    int H, int lw, int lhw, int off_l)
{
    const int W   = 1 << lw;
    const int Wp  = W + 2;
    const int HW  = 1 << lhw;
    const int tid = threadIdx.x;
    const int m_base = blockIdx.x * 128;
    const int b   = m_base >> lhw;
    const int mi  = m_base & (HW - 1);
    const int y0  = mi >> lw;
    const int ibase = b * (H + 2) * Wp * 256;

    __shared__ __align__(16) bf16 Als[128 * 64];
    __shared__ __align__(16) bf16 Bls[NB * 16 * 64];

    const int ch8   = (((tid & 7) ^ ((tid >> 3) & 7)) << 3);
    const int rbase = tid >> 3;
    int ag[4];
#pragma unroll
    for (int i = 0; i < 4; ++i) {
        int row = i * 32 + rbase;
        int y = y0 + (row >> lw);
        int x = row & (W - 1);
        ag[i] = ibase + (y * Wp + x) * 256 + ch8;
    }

    f32x4 acc[2][NB];
#pragma unroll
    for (int i = 0; i < 2; ++i)
#pragma unroll
        for (int j = 0; j < NB; ++j)
            acc[i][j] = (f32x4)(0.0f);

    const int lane = tid & 63;
    const int wv   = tid >> 6;      // wave handles m rows [wv*32, wv*32+32)
    const int l16  = lane & 15;
    const int quad = lane >> 4;
    const int xsw  = l16 & 7;
    const int aRow = (wv * 32 + l16) * 64;
    const int bRow = l16 * 64;
    bf16* lA = Als + tid * 8;

    for (int kc = 0; kc < 36; ++kc) {
        const int t  = kc >> 2;
        const int dy = t / 3;
        const int dx = t - dy * 3;
        const int c0 = (kc & 3) << 6;
        const int aoff = (dy * Wp + dx) * 256 + c0;
#pragma unroll
        for (int i = 0; i < 4; ++i)
            gl_lds16(A + ag[i] + aoff, lA + i * 2048);
        // B tile via plain loads (weights tiny, L2-resident); store swizzled
        for (int s = tid; s < NB * 128; s += 256) {
            int row = s >> 3;
            int gc  = s & 7;                 // global chunk
            int lc  = gc ^ (row & 7);        // swizzled LDS chunk
            *(uint4*)(Bls + row * 64 + (lc << 3)) =
                *(const uint4*)(BT + (t * (NB * 16) + row) * 256 + c0 + (gc << 3));
        }
        __syncthreads();
#pragma unroll
        for (int ks = 0; ks < 2; ++ks) {
            const int cO = (((quad + ks * 4) ^ xsw) << 3);
            bf16x8 af[2], bfv[NB];
#pragma unroll
            for (int i = 0; i < 2; ++i)
                af[i] = *(const bf16x8*)(Als + aRow + i * (16 * 64) + cO);
#pragma unroll
            for (int j = 0; j < NB; ++j)
                bfv[j] = *(const bf16x8*)(Bls + bRow + j * (16 * 64) + cO);
#pragma unroll
            for (int i = 0; i < 2; ++i)
#pragma unroll
                for (int j = 0; j < NB; ++j)
                    acc[i][j] = __builtin_amdgcn_mfma_f32_16x16x32_bf16(
                        af[i], bfv[j], acc[i][j], 0, 0, 0);
        }
        __syncthreads();
    }

#pragma unroll
    for (int i = 0; i < 2; ++i) {
#pragma unroll
        for (int r = 0; r < 4; ++r) {
            const int ml  = wv * 32 + i * 16 + quad * 4 + r;
            const int pos = mi + ml;
            const int ob  = (b * 5376 + off_l + pos) * 85 + J0;
#pragma unroll
            for (int j = 0; j < NB; ++j) {
                const int n = j * 16 + l16;
                if (NVALID == NB * 16 || n < NVALID)
                    out[ob + n] = acc[i][j][r] + bias[n];
            }
        }
    }
}

// ---------------------------------------------------------------------------
// Layout transforms
// ---------------------------------------------------------------------------

// fp32 NCHW -> padded NHWC bf16 (interior only; borders pre-zeroed)
__global__ void cast_pad_kernel(const float* __restrict__ in, bf16* __restrict__ out,
                                int H, int lw)
{
    const int c  = threadIdx.x;
    const int hw = blockIdx.x;
    const int b  = blockIdx.y;
    const int W  = 1 << lw;
    const int y  = hw >> lw;
    const int x  = hw & (W - 1);
    float v = in[((b * 256 + c) * H + y) * W + x];
    out[((b * (H + 2) + y + 1) * (W + 2) + (x + 1)) * 256 + c] = (bf16)v;
}

// stem weights (S,co,ci,3,3) fp32 -> [s][t][co][ci] bf16
__global__ void prepack_stem_kernel(const float* __restrict__ w, bf16* __restrict__ o)
{
    const int ci = threadIdx.x;
    const int g  = blockIdx.x;          // (s*9+t)*256 + co, g < 9216
    const int co = g & 255;
    const int st = g >> 8;
    const int s  = st / 9;
    const int t  = st - s * 9;
    o[(size_t)g * 256 + ci] = (bf16)w[(((s * 256 + co) * 256 + ci) * 9) + t];
}

// pred weights -> [t][80][256] (cls) and [t][16][256] (box 0..3, ctr 4, pad 0)
__global__ void prepack_pred_kernel(const float* __restrict__ wc,
                                    const float* __restrict__ wb,
                                    const float* __restrict__ wr,
                                    const float* __restrict__ bb,
                                    const float* __restrict__ br,
                                    bf16* __restrict__ oc, bf16* __restrict__ obc,
                                    float* __restrict__ obias)
{
    const int ci = threadIdx.x;
    const int g  = blockIdx.x;          // 0 .. 9*85-1
    const int t  = g / 85;
    const int co = g - t * 85;
    if (co < 80) {
        oc[((t * 80 + co) * 256) + ci] = (bf16)wc[((co * 256 + ci) * 9) + t];
    } else {
        const int c2 = co - 80;         // 0..4
        float v = (c2 < 4) ? wb[((c2 * 256 + ci) * 9) + t] : wr[(ci * 9) + t];
        obc[((t * 16 + c2) * 256) + ci] = (bf16)v;
    }
    if (g == 0 && ci < 16)
        obias[ci] = (ci < 4) ? bb[ci] : (ci == 4 ? br[0] : 0.0f);
}

// ---------------------------------------------------------------------------
extern "C" void kernel_launch(void* const* d_in, const int* in_sizes, int n_in,
                              void* d_out, int out_size, void* d_ws, size_t ws_size,
                              hipStream_t stream)
{
    (void)in_sizes; (void)n_in; (void)out_size;
    const float* feat[3] = {(const float*)d_in[0], (const float*)d_in[1],
                            (const float*)d_in[2]};
    const float* scw = (const float*)d_in[3];
    const float* scb = (const float*)d_in[4];
    const float* sbw = (const float*)d_in[5];
    const float* sbb = (const float*)d_in[6];
    const float* pcw = (const float*)d_in[7];
    const float* pcb = (const float*)d_in[8];
    const float* pbw = (const float*)d_in[9];
    const float* pbb = (const float*)d_in[10];
    const float* prw = (const float*)d_in[11];
    const float* prb = (const float*)d_in[12];
    float* out = (float*)d_out;

    char* ws = (char*)d_ws;
    const size_t BUF3 = (size_t)16 * 66 * 66 * 256 * 2;  // 35,684,352 B
    size_t off = 5 * BUF3;                                // 5 act buffers (p3-sized)
    bf16*  wbTc = (bf16*)(ws + off); off += (size_t)4 * 9 * 256 * 256 * 2;
    bf16*  wbTb = (bf16*)(ws + off); off += (size_t)4 * 9 * 256 * 256 * 2;
    bf16*  pcT  = (bf16*)(ws + off); off += (size_t)9 * 80 * 256 * 2;
    bf16*  pbcT = (bf16*)(ws + off); off += (size_t)9 * 16 * 256 * 2;
    float* pbcB = (float*)(ws + off); off += 256;
    if (ws_size < off) return;  // ~188.3 MB required

    // zero everything once: act borders, pbcT pad rows, bias pad
    hipMemsetAsync(d_ws, 0, off, stream);

    prepack_stem_kernel<<<dim3(9216), 256, 0, stream>>>(scw, wbTc);
    prepack_stem_kernel<<<dim3(9216), 256, 0, stream>>>(sbw, wbTb);
    prepack_pred_kernel<<<dim3(9 * 85), 256, 0, stream>>>(pcw, pbw, prw, pbb, prb,
                                                          pcT, pbcT, pbcB);

    const int Hs[3]   = {64, 32, 16};
    const int lws[3]  = {6, 5, 4};
    const int lhws[3] = {12, 10, 8};
    const int offl[3] = {0, 4096, 5120};

    for (int l = 0; l < 3; ++l) {
        const int H = Hs[l], lw = lws[l], lhw = lhws[l];
        const size_t buf = (size_t)16 * (H + 2) * (H + 2) * 256 * 2;
        bf16* X0  = (bf16*)(ws);
        bf16* Xc1 = (bf16*)(ws + buf);
        bf16* Xc2 = (bf16*)(ws + 2 * buf);
        bf16* Xb1 = (bf16*)(ws + 3 * buf);
        bf16* Xb2 = (bf16*)(ws + 4 * buf);
        if (l > 0)  // re-zero borders for the smaller geometry
            hipMemsetAsync(ws, 0, 5 * buf, stream);

        cast_pad_kernel<<<dim3(H * H, 16), 256, 0, stream>>>(feat[l], X0, H, lw);

        const int M = 16 << lhw;
        const bf16* inC = X0;
        const bf16* inB = X0;
        for (int s = 0; s < 4; ++s) {
            bf16* oc = (s & 1) ? Xc2 : Xc1;
            bf16* ob = (s & 1) ? Xb2 : Xb1;
            const bf16* wc = wbTc + (size_t)s * 589824;
            const bf16* wb = wbTb + (size_t)s * 589824;
            if (l < 2) {
                stem_conv_kernel<128, 128><<<dim3(M / 128, 2, 2), 256, 0, stream>>>(
                    inC, inB, oc, ob, wc, wb, scb + s * 256, sbb + s * 256,
                    H, lw, lhw);
            } else {  // p5: small M -> 64x64 tiles for 512 blocks
                stem_conv_kernel<64, 64><<<dim3(M / 64, 4, 2), 256, 0, stream>>>(
                    inC, inB, oc, ob, wc, wb, scb + s * 256, sbb + s * 256,
                    H, lw, lhw);
            }
            inC = oc;
            inB = ob;
        }
        pred_conv_kernel<5, 80, 0><<<dim3(M / 128), 256, 0, stream>>>(
            inC, pcT, pcb, out, H, lw, lhw, offl[l]);
        pred_conv_kernel<1, 5, 80><<<dim3(M / 128), 256, 0, stream>>>(
            inB, pbcT, pbcB, out, H, lw, lhw, offl[l]);
    }
}

// Round 3
// 1502.283 us; speedup vs baseline: 1.2023x; 1.0465x over previous
//
#include <hip/hip_runtime.h>

// ---------------------------------------------------------------------------
// FCOS head on MI355X: bf16 MFMA implicit-GEMM 3x3 convs (m97 structure).
//   activations: padded NHWC bf16, [B][H+2][W+2][256], zero borders
//   stem weights: [s][tap][co][ci] bf16 (B^T, row-contiguous in ci)
//   pred weights: [tap][96][ci] bf16 (rows 0..79 cls, 80..83 box, 84 ctr, pad)
// GEMM per conv: M = B*H*W, N = co, K = 9*256 (chunks of 64, tap-aligned)
//
// LDS XOR-swizzle everywhere: LDS row r, 16B-chunk c holds GLOBAL chunk
// c ^ (r&7) (kills 16-way ds_read_b128 conflicts; verified R2: 5.66e7 -> 0).
// Epilogue: wave-private LDS transpose -> coalesced 16B global stores.
// All 3 FPN levels fused per dispatch (identical 128x128 tiles).
// ---------------------------------------------------------------------------

typedef __bf16 bf16;
typedef __attribute__((ext_vector_type(8))) __bf16 bf16x8;
typedef __attribute__((ext_vector_type(4))) float f32x4;

typedef unsigned int uint32_as1 __attribute__((address_space(1)));
typedef unsigned int uint32_as3 __attribute__((address_space(3)));

__device__ __forceinline__ void gl_lds16(const bf16* g, bf16* l) {
    __builtin_amdgcn_global_load_lds(
        (const uint32_as1*)(unsigned long long)g,
        (uint32_as3*)(unsigned int)(unsigned long long)l,
        16, 0, 0);
}

struct StemTab {
    const bf16* inC[3]; const bf16* inB[3];
    bf16* outC[3]; bf16* outB[3];
    int H[3]; int lw[3]; int lhw[3];
    int xend0, xend1;
};

struct PredTab {
    const bf16* inC[3]; const bf16* inB[3];
    int H[3]; int lw[3]; int lhw[3]; int offl[3];
    int xend0, xend1;
};

// ---------------------------------------------------------------------------
// Stem conv, 128x128 tile, BK=64, 4 waves (2x2), dual-path via z, fused levels.
// ---------------------------------------------------------------------------
__global__ __launch_bounds__(256) void stem_conv_kernel(
    StemTab tab, const bf16* __restrict__ Wc, const bf16* __restrict__ Wb,
    const float* __restrict__ bc, const float* __restrict__ bb)
{
    const int bx = blockIdx.x;
    const int l  = (bx >= tab.xend0) + (bx >= tab.xend1);
    const int start = (l == 0) ? 0 : (l == 1 ? tab.xend0 : tab.xend1);
    const int local = bx - start;
    const int H = tab.H[l], lw = tab.lw[l], lhw = tab.lhw[l];

    const bf16* A; bf16* O; const bf16* BT; const float* bias;
    if (blockIdx.z == 0) { A = tab.inC[l]; O = tab.outC[l]; BT = Wc; bias = bc; }
    else                 { A = tab.inB[l]; O = tab.outB[l]; BT = Wb; bias = bb; }

    const int W   = 1 << lw;
    const int Wp  = W + 2;
    const int HW  = 1 << lhw;
    const int tid = threadIdx.x;
    const int m_base = (local >> 1) * 128;
    const int n0     = (local & 1) * 128;
    const int b   = m_base >> lhw;
    const int y0  = (m_base & (HW - 1)) >> lw;
    const int ibase = b * (H + 2) * Wp * 256;

    __shared__ __align__(16) bf16 Sh[128 * 64 * 2];   // staging A|B, later T
    bf16* Als = Sh;
    bf16* Bls = Sh + 8192;

    // staging: lane tid -> LDS row tid/8, chunk tid%8; global chunk XOR'd.
    const int ch8   = (((tid & 7) ^ ((tid >> 3) & 7)) << 3);
    const int rbase = tid >> 3;
    int ag[4], bg[4];
#pragma unroll
    for (int i = 0; i < 4; ++i) {
        int row = i * 32 + rbase;
        int y = y0 + (row >> lw);
        int x = row & (W - 1);
        ag[i] = ibase + (y * Wp + x) * 256 + ch8;
        bg[i] = (n0 + row) * 256 + ch8;
    }

    f32x4 acc[4][4];
#pragma unroll
    for (int i = 0; i < 4; ++i)
#pragma unroll
        for (int j = 0; j < 4; ++j)
            acc[i][j] = (f32x4)(0.0f);

    const int lane = tid & 63;
    const int wv   = tid >> 6;
    const int wm   = (wv & 1) * 64;
    const int wn   = (wv >> 1) * 64;
    const int l16  = lane & 15;
    const int quad = lane >> 4;
    const int xsw  = l16 & 7;
    const int aRow = (wm + l16) * 64;
    const int bRow = (wn + l16) * 64;
    bf16* lA = Als + tid * 8;
    bf16* lB = Bls + tid * 8;

    for (int kc = 0; kc < 36; ++kc) {
        const int t  = kc >> 2;
        const int dy = t / 3;
        const int dx = t - dy * 3;
        const int c0 = (kc & 3) << 6;
        const int aoff = (dy * Wp + dx) * 256 + c0;
        const int boff = t * 65536 + c0;
#pragma unroll
        for (int i = 0; i < 4; ++i)
            gl_lds16(A + ag[i] + aoff, lA + i * 2048);
#pragma unroll
        for (int i = 0; i < 4; ++i)
            gl_lds16(BT + bg[i] + boff, lB + i * 2048);
        __syncthreads();
#pragma unroll
        for (int ks = 0; ks < 2; ++ks) {
            const int cO = (((quad + ks * 4) ^ xsw) << 3);
            bf16x8 af[4], bfv[4];
#pragma unroll
            for (int i = 0; i < 4; ++i)
                af[i] = *(const bf16x8*)(Als + aRow + i * 1024 + cO);
#pragma unroll
            for (int j = 0; j < 4; ++j)
                bfv[j] = *(const bf16x8*)(Bls + bRow + j * 1024 + cO);
#pragma unroll
            for (int i = 0; i < 4; ++i)
#pragma unroll
                for (int j = 0; j < 4; ++j)
                    acc[i][j] = __builtin_amdgcn_mfma_f32_16x16x32_bf16(
                        af[i], bfv[j], acc[i][j], 0, 0, 0);
        }
        __syncthreads();
    }

    // ---- epilogue: bias+relu+cvt -> wave-private swizzled T -> 16B stores
    float bv[4];
#pragma unroll
    for (int j = 0; j < 4; ++j) bv[j] = bias[n0 + wn + j * 16 + l16];
    bf16* Tw = Sh + wv * 4096;                    // 64x64 bf16, chunk-swizzled
#pragma unroll
    for (int i = 0; i < 4; ++i)
#pragma unroll
        for (int r = 0; r < 4; ++r) {
            const int row = i * 16 + quad * 4 + r;
#pragma unroll
            for (int j = 0; j < 4; ++j) {
                float v = acc[i][j][r] + bv[j];
                v = v > 0.0f ? v : 0.0f;
                const int sc = (((j * 2 + (l16 >> 3)) ^ (row & 7)) << 3) + (l16 & 7);
                Tw[row * 64 + sc] = (bf16)v;
            }
        }
    __syncthreads();
    const int rgrp = lane >> 3, cc = lane & 7;
#pragma unroll
    for (int p = 0; p < 8; ++p) {
        const int row = p * 8 + rgrp;
        bf16x8 vv = *(const bf16x8*)(Tw + row * 64 + ((cc ^ (row & 7)) << 3));
        const int ml = wm + row;
        const int y  = y0 + (ml >> lw);
        const int x  = ml & (W - 1);
        *(bf16x8*)(O + ibase + ((y + 1) * Wp + (x + 1)) * 256 + n0 + wn + cc * 8) = vv;
    }
}

// ---------------------------------------------------------------------------
// Fused prediction conv (cls 80 cols from cls-feat + box/ctr 5 cols from
// box-feat). M-tile 128; writes fp32 straight into d_out (B,5376,85).
// ---------------------------------------------------------------------------
__global__ __launch_bounds__(256) void pred_conv_kernel(
    PredTab tab, const bf16* __restrict__ BT, const float* __restrict__ bias,
    float* __restrict__ out)
{
    const int bx = blockIdx.x;
    const int l  = (bx >= tab.xend0) + (bx >= tab.xend1);
    const int start = (l == 0) ? 0 : (l == 1 ? tab.xend0 : tab.xend1);
    const int mt = bx - start;
    const int H = tab.H[l], lw = tab.lw[l], lhw = tab.lhw[l], off_l = tab.offl[l];
    const bf16* Ac = tab.inC[l];
    const bf16* Ab = tab.inB[l];

    const int W   = 1 << lw;
    const int Wp  = W + 2;
    const int HW  = 1 << lhw;
    const int tid = threadIdx.x;
    const int m_base = mt * 128;
    const int b   = m_base >> lhw;
    const int mi  = m_base & (HW - 1);
    const int y0  = mi >> lw;
    const int ibase = b * (H + 2) * Wp * 256;

    __shared__ __align__(16) bf16 Sh[(128 + 128 + 96) * 64];  // Ac|Ab|B

    const int ch8   = (((tid & 7) ^ ((tid >> 3) & 7)) << 3);
    const int rbase = tid >> 3;
    int ag[4], bg[3];
#pragma unroll
    for (int i = 0; i < 4; ++i) {
        int row = i * 32 + rbase;
        int y = y0 + (row >> lw);
        int x = row & (W - 1);
        ag[i] = ibase + (y * Wp + x) * 256 + ch8;
    }
#pragma unroll
    for (int i = 0; i < 3; ++i)
        bg[i] = (i * 32 + rbase) * 256 + ch8;

    f32x4 accC[2][5], accB[2];
#pragma unroll
    for (int i = 0; i < 2; ++i) {
#pragma unroll
        for (int j = 0; j < 5; ++j) accC[i][j] = (f32x4)(0.0f);
        accB[i] = (f32x4)(0.0f);
    }

    const int lane = tid & 63;
    const int wv   = tid >> 6;
    const int l16  = lane & 15;
    const int quad = lane >> 4;
    const int xsw  = l16 & 7;
    const int aRow = (wv * 32 + l16) * 64;
    bf16* lS = Sh + tid * 8;

    for (int kc = 0; kc < 36; ++kc) {
        const int t  = kc >> 2;
        const int dy = t / 3;
        const int dx = t - dy * 3;
        const int c0 = (kc & 3) << 6;
        const int aoff = (dy * Wp + dx) * 256 + c0;
        const int boff = t * 24576 + c0;          // t*96*256
#pragma unroll
        for (int i = 0; i < 4; ++i)
            gl_lds16(Ac + ag[i] + aoff, lS + i * 2048);
#pragma unroll
        for (int i = 0; i < 4; ++i)
            gl_lds16(Ab + ag[i] + aoff, lS + (4 + i) * 2048);
#pragma unroll
        for (int i = 0; i < 3; ++i)
            gl_lds16(BT + bg[i] + boff, lS + (8 + i) * 2048);
        __syncthreads();
#pragma unroll
        for (int ks = 0; ks < 2; ++ks) {
            const int cO = (((quad + ks * 4) ^ xsw) << 3);
            bf16x8 afc[2], afb[2], bfv[5], bfb;
#pragma unroll
            for (int i = 0; i < 2; ++i) {
                afc[i] = *(const bf16x8*)(Sh + aRow + i * 1024 + cO);
                afb[i] = *(const bf16x8*)(Sh + 8192 + aRow + i * 1024 + cO);
            }
#pragma unroll
            for (int j = 0; j < 5; ++j)
                bfv[j] = *(const bf16x8*)(Sh + 16384 + (j * 16 + l16) * 64 + cO);
            bfb = *(const bf16x8*)(Sh + 16384 + (80 + l16) * 64 + cO);
#pragma unroll
            for (int i = 0; i < 2; ++i) {
#pragma unroll
                for (int j = 0; j < 5; ++j)
                    accC[i][j] = __builtin_amdgcn_mfma_f32_16x16x32_bf16(
                        afc[i], bfv[j], accC[i][j], 0, 0, 0);
                accB[i] = __builtin_amdgcn_mfma_f32_16x16x32_bf16(
                    afb[i], bfb, accB[i], 0, 0, 0);
            }
        }
        __syncthreads();
    }

#pragma unroll
    for (int i = 0; i < 2; ++i) {
#pragma unroll
        for (int r = 0; r < 4; ++r) {
            const int ml  = wv * 32 + i * 16 + quad * 4 + r;
            const int pos = mi + ml;
            const int ob  = (b * 5376 + off_l + pos) * 85;
#pragma unroll
            for (int j = 0; j < 5; ++j)
                out[ob + j * 16 + l16] = accC[i][j][r] + bias[j * 16 + l16];
            if (l16 < 5)
                out[ob + 80 + l16] = accB[i][r] + bias[80 + l16];
        }
    }
}

// ---------------------------------------------------------------------------
// Layout transforms / init
// ---------------------------------------------------------------------------
__global__ void cast_pad_kernel(const float* __restrict__ in, bf16* __restrict__ out,
                                int H, int lw)
{
    const int c  = threadIdx.x;
    const int hw = blockIdx.x;
    const int b  = blockIdx.y;
    const int W  = 1 << lw;
    const int y  = hw >> lw;
    const int x  = hw & (W - 1);
    float v = in[((b * 256 + c) * H + y) * W + x];
    out[((b * (H + 2) + y + 1) * (W + 2) + (x + 1)) * 256 + c] = (bf16)v;
}

// zero borders of 5 contiguous padded buffers (one block = one border px)
__global__ void border_zero_kernel(bf16* base, int H, size_t bufElems, int pxPerImg)
{
    const int i   = blockIdx.x;
    const int buf = blockIdx.y;
    const int c   = threadIdx.x;
    const int img = i / pxPerImg;
    const int p   = i - img * pxPerImg;
    const int Wp  = H + 2, Hp = H + 2;
    int y, xp;
    if (p < Wp)            { y = 0;      xp = p; }
    else if (p < 2 * Wp)   { y = Hp - 1; xp = p - Wp; }
    else { int q = p - 2 * Wp; y = 1 + (q >> 1); xp = (q & 1) ? (Wp - 1) : 0; }
    base[buf * bufElems + ((size_t)(img * Hp + y) * Wp + xp) * 256 + c] = (bf16)0.0f;
}

// stem weights (S,co,ci,3,3) fp32 -> [s][t][co][ci] bf16
__global__ void prepack_stem_kernel(const float* __restrict__ w, bf16* __restrict__ o)
{
    const int ci = threadIdx.x;
    const int g  = blockIdx.x;          // (s*9+t)*256 + co
    const int co = g & 255;
    const int st = g >> 8;
    const int s  = st / 9;
    const int t  = st - s * 9;
    o[(size_t)g * 256 + ci] = (bf16)w[(((s * 256 + co) * 256 + ci) * 9) + t];
}

// pred weights -> [t][96][256]: rows 0..79 cls, 80..83 box, 84 ctr, 85..95 pad
__global__ void prepack_pred_kernel(const float* __restrict__ wc,
                                    const float* __restrict__ wb,
                                    const float* __restrict__ wr,
                                    const float* __restrict__ cb,
                                    const float* __restrict__ bb,
                                    const float* __restrict__ br,
                                    bf16* __restrict__ oT, float* __restrict__ obias)
{
    const int ci = threadIdx.x;
    const int g  = blockIdx.x;          // 0 .. 9*96-1
    const int t  = g / 96;
    const int co = g - t * 96;
    float v = 0.0f;
    if (co < 80)       v = wc[((co * 256 + ci) * 9) + t];
    else if (co < 84)  v = wb[(((co - 80) * 256 + ci) * 9) + t];
    else if (co == 84) v = wr[(ci * 9) + t];
    oT[(size_t)g * 256 + ci] = (bf16)v;
    if (g == 0 && ci < 96) {
        float bvv = 0.0f;
        if (ci < 80)       bvv = cb[ci];
        else if (ci < 84)  bvv = bb[ci - 80];
        else if (ci == 84) bvv = br[0];
        obias[ci] = bvv;
    }
}

// ---------------------------------------------------------------------------
extern "C" void kernel_launch(void* const* d_in, const int* in_sizes, int n_in,
                              void* d_out, int out_size, void* d_ws, size_t ws_size,
                              hipStream_t stream)
{
    (void)in_sizes; (void)n_in; (void)out_size;
    const float* feat[3] = {(const float*)d_in[0], (const float*)d_in[1],
                            (const float*)d_in[2]};
    const float* scw = (const float*)d_in[3];
    const float* scb = (const float*)d_in[4];
    const float* sbw = (const float*)d_in[5];
    const float* sbb = (const float*)d_in[6];
    const float* pcw = (const float*)d_in[7];
    const float* pcb = (const float*)d_in[8];
    const float* pbw = (const float*)d_in[9];
    const float* pbb = (const float*)d_in[10];
    const float* prw = (const float*)d_in[11];
    const float* prb = (const float*)d_in[12];
    float* out = (float*)d_out;

    const int Hs[3]   = {64, 32, 16};
    const int lws[3]  = {6, 5, 4};
    const int lhws[3] = {12, 10, 8};
    const int offl[3] = {0, 4096, 5120};
    const int mtiles[3] = {512, 128, 32};          // M/128 per level
    size_t bufB[3];
    for (int l = 0; l < 3; ++l)
        bufB[l] = (size_t)16 * (Hs[l] + 2) * (Hs[l] + 2) * 256 * 2;

    const size_t WSTEM = (size_t)4 * 9 * 256 * 256 * 2;
    const size_t WPRED = (size_t)9 * 96 * 256 * 2;
    const size_t FULL   = 5 * (bufB[0] + bufB[1] + bufB[2]) + 2 * WSTEM + WPRED + 384;
    const size_t SHARED = 5 * bufB[0] + 2 * WSTEM + WPRED + 384;
    if (ws_size < SHARED) return;
    const bool fused = ws_size >= FULL;

    char* ws = (char*)d_ws;
    bf16* act[3][5];
    size_t off = 0;
    if (fused) {
        for (int l = 0; l < 3; ++l)
            for (int k = 0; k < 5; ++k) { act[l][k] = (bf16*)(ws + off); off += bufB[l]; }
    } else {
        for (int k = 0; k < 5; ++k)
            for (int l = 0; l < 3; ++l) act[l][k] = (bf16*)(ws + (size_t)k * bufB[0]);
        off = 5 * bufB[0];
    }
    bf16*  wbTc = (bf16*)(ws + off); off += WSTEM;
    bf16*  wbTb = (bf16*)(ws + off); off += WSTEM;
    bf16*  pT   = (bf16*)(ws + off); off += WPRED;
    float* pB   = (float*)(ws + off);

    prepack_stem_kernel<<<dim3(9216), 256, 0, stream>>>(scw, wbTc);
    prepack_stem_kernel<<<dim3(9216), 256, 0, stream>>>(sbw, wbTb);
    prepack_pred_kernel<<<dim3(9 * 96), 256, 0, stream>>>(pcw, pbw, prw, pcb, pbb, prb,
                                                          pT, pB);

    auto launch_level_init = [&](int l) {
        const int H = Hs[l];
        const int px = 2 * (H + 2) + 2 * H;
        border_zero_kernel<<<dim3(16 * px, 5), 256, 0, stream>>>(
            act[l][0], H, bufB[l] / 2, px);
        cast_pad_kernel<<<dim3(H * H, 16), 256, 0, stream>>>(feat[l], act[l][0], H, lws[l]);
    };

    auto make_stem_tab = [&](int s, int nlev, const int* levs) {
        StemTab tb{};
        for (int i = 0; i < nlev; ++i) {
            int l = levs[i];
            tb.inC[i]  = (s == 0) ? act[l][0] : ((s & 1) ? act[l][1] : act[l][2]);
            tb.inB[i]  = (s == 0) ? act[l][0] : ((s & 1) ? act[l][3] : act[l][4]);
            tb.outC[i] = (s & 1) ? act[l][2] : act[l][1];
            tb.outB[i] = (s & 1) ? act[l][4] : act[l][3];
            tb.H[i] = Hs[l]; tb.lw[i] = lws[l]; tb.lhw[i] = lhws[l];
        }
        return tb;
    };

    if (fused) {
        for (int l = 0; l < 3; ++l) launch_level_init(l);
        const int levs[3] = {0, 1, 2};
        const int tx0 = mtiles[0] * 2, tx1 = mtiles[1] * 2, tx2 = mtiles[2] * 2;
        for (int s = 0; s < 4; ++s) {
            StemTab tb = make_stem_tab(s, 3, levs);
            tb.xend0 = tx0; tb.xend1 = tx0 + tx1;
            stem_conv_kernel<<<dim3(tx0 + tx1 + tx2, 1, 2), 256, 0, stream>>>(
                tb, wbTc + (size_t)s * 589824, wbTb + (size_t)s * 589824,
                scb + s * 256, sbb + s * 256);
        }
        PredTab pt{};
        for (int l = 0; l < 3; ++l) {
            pt.inC[l] = act[l][2]; pt.inB[l] = act[l][4];
            pt.H[l] = Hs[l]; pt.lw[l] = lws[l]; pt.lhw[l] = lhws[l]; pt.offl[l] = offl[l];
        }
        pt.xend0 = mtiles[0]; pt.xend1 = mtiles[0] + mtiles[1];
        pred_conv_kernel<<<dim3(mtiles[0] + mtiles[1] + mtiles[2]), 256, 0, stream>>>(
            pt, pT, pB, out);
    } else {
        for (int l = 0; l < 3; ++l) {
            launch_level_init(l);
            const int levs[1] = {l};
            const int tiles = mtiles[l] * 2;
            for (int s = 0; s < 4; ++s) {
                StemTab tb = make_stem_tab(s, 1, levs);
                tb.xend0 = tiles; tb.xend1 = tiles;
                stem_conv_kernel<<<dim3(tiles, 1, 2), 256, 0, stream>>>(
                    tb, wbTc + (size_t)s * 589824, wbTb + (size_t)s * 589824,
                    scb + s * 256, sbb + s * 256);
            }
            PredTab pt{};
            pt.inC[0] = act[l][2]; pt.inB[0] = act[l][4];
            pt.H[0] = Hs[l]; pt.lw[0] = lws[l]; pt.lhw[0] = lhws[l]; pt.offl[0] = offl[l];
            pt.xend0 = mtiles[l]; pt.xend1 = mtiles[l];
            pred_conv_kernel<<<dim3(mtiles[l]), 256, 0, stream>>>(pt, pT, pB, out);
        }
    }
}

// Round 5
// 1114.366 us; speedup vs baseline: 1.6209x; 1.3481x over previous
//
#include <hip/hip_runtime.h>

// ---------------------------------------------------------------------------
// FCOS head on MI355X: bf16 MFMA implicit-GEMM 3x3 convs.
//   activations: padded NHWC bf16, [B][H+2][W+2][256], zero borders
//   stem weights: [s][tap][co][ci] bf16 (B^T, row-contiguous in ci)
//   pred weights: [tap][96][ci] bf16 (rows 0..79 cls, 80..83 box, 84 ctr, pad)
//
// R2: XOR chunk-swizzled LDS (LDS row r chunk c holds global chunk c^(r&7))
//     -> SQ_LDS_BANK_CONFLICT 5.66e7 -> 0 (verified).
// R3: vectorized epilogue via wave-private LDS transpose; level-fused grids.
// R4: tap-row A staging (stage R*(W+2) contiguous px once per (dy,chunk);
//     3 dx taps served from LDS via p = m + 2*(m>>lw) + dx). Crashed: tail
//     staging slot was issued under a divergent branch -> global_load_lds
//     with partial EXEC (untested HW corner, m104/m108).
// R5: tail slot made exec-uniform: all lanes always issue it; out-of-window
//     lanes clamp their per-lane GLOBAL address into the window (LDS rows
//     >= window are written-but-never-read). LDS A region = 160 rows.
// ---------------------------------------------------------------------------

typedef __bf16 bf16;
typedef __attribute__((ext_vector_type(8))) __bf16 bf16x8;
typedef __attribute__((ext_vector_type(4))) float f32x4;

typedef unsigned int uint32_as1 __attribute__((address_space(1)));
typedef unsigned int uint32_as3 __attribute__((address_space(3)));

__device__ __forceinline__ void gl_lds16(const bf16* g, bf16* l) {
    __builtin_amdgcn_global_load_lds(
        (const uint32_as1*)(unsigned long long)g,
        (uint32_as3*)(unsigned int)(unsigned long long)l,
        16, 0, 0);
}

struct StemTab {
    const bf16* inC[3]; const bf16* inB[3];
    bf16* outC[3]; bf16* outB[3];
    int H[3]; int lw[3]; int lhw[3];
    int xend0, xend1;
};

struct PredTab {
    const bf16* inC[3]; const bf16* inB[3];
    int H[3]; int lw[3]; int lhw[3]; int offl[3];
    int xend0, xend1;
};

// ---------------------------------------------------------------------------
// Stem conv, 128x128 tile, 4 waves (2x2 of 64x64), dual-path via z, fused
// levels. K-loop: dy (3) x c-chunk (4) x dx (3); A staged once per (dy,chunk).
// ---------------------------------------------------------------------------
__global__ __launch_bounds__(256) void stem_conv_kernel(
    StemTab tab, const bf16* __restrict__ Wc, const bf16* __restrict__ Wb,
    const float* __restrict__ bc, const float* __restrict__ bb)
{
    const int bx = blockIdx.x;
    const int l  = (bx >= tab.xend0) + (bx >= tab.xend1);
    const int start = (l == 0) ? 0 : (l == 1 ? tab.xend0 : tab.xend1);
    const int local = bx - start;
    const int H = tab.H[l], lw = tab.lw[l], lhw = tab.lhw[l];

    const bf16* A; bf16* O; const bf16* BT; const float* bias;
    if (blockIdx.z == 0) { A = tab.inC[l]; O = tab.outC[l]; BT = Wc; bias = bc; }
    else                 { A = tab.inB[l]; O = tab.outB[l]; BT = Wb; bias = bb; }

    const int W   = 1 << lw;
    const int Wp  = W + 2;
    const int HW  = 1 << lhw;
    const int tid = threadIdx.x;
    const int m_base = (local >> 1) * 128;
    const int n0     = (local & 1) * 128;
    const int b   = m_base >> lhw;
    const int y0  = (m_base & (HW - 1)) >> lw;     // tile = R image rows
    const int ibase = b * (H + 2) * Wp * 256;

    // LDS: A = 160 px rows x 64ch (10240 elems), B = 128 co rows x 64 (8192)
    __shared__ __align__(16) bf16 Sh[18432];
    bf16* Als = Sh;
    bf16* Bls = Sh + 10240;

    const int ch8   = (((tid & 7) ^ ((tid >> 3) & 7)) << 3);
    const int rbase = tid >> 3;
    const int Wp256 = Wp * 256;
    const int npx   = (128 >> lw) * Wp;            // window px: 132/136/144
    // tail slot: exec-uniform issue; clamp OOW lanes' global addr into window
    const int toff  = (128 + rbase < npx) ? 4 * 8192 : 0;
    const int ag0   = ibase + rbase * 256 + ch8;
    int bg[4];
#pragma unroll
    for (int i = 0; i < 4; ++i)
        bg[i] = (n0 + i * 32 + rbase) * 256 + ch8;

    f32x4 acc[4][4];
#pragma unroll
    for (int i = 0; i < 4; ++i)
#pragma unroll
        for (int j = 0; j < 4; ++j)
            acc[i][j] = (f32x4)(0.0f);

    const int lane = tid & 63;
    const int wv   = tid >> 6;
    const int wm   = (wv & 1) * 64;
    const int wn   = (wv >> 1) * 64;
    const int l16  = lane & 15;
    const int quad = lane >> 4;
    // A fragment px-row base per i (excl dx): p(m) = m + 2*(m>>lw) + dx;
    // fragments never cross an image row (W >= 16, mm multiple of 16)
    int pb[4];
#pragma unroll
    for (int i = 0; i < 4; ++i) {
        const int mm = wm + i * 16;
        pb[i] = mm + ((mm >> lw) << 1) + l16;
    }
    const int bRow = (wn + l16) * 64;
    const int bsw  = l16 & 7;
    bf16* lA = Als + tid * 8;
    bf16* lB = Bls + tid * 8;

    for (int dy = 0; dy < 3; ++dy) {
        const int abase = ag0 + (y0 + dy) * Wp256;
        for (int cq = 0; cq < 4; ++cq) {
            const int c0 = cq << 6;
            // ---- stage A window: R*(W+2) px, contiguous in global ----
#pragma unroll
            for (int i = 0; i < 4; ++i)
                gl_lds16(A + abase + c0 + i * 8192, lA + i * 2048);
            gl_lds16(A + abase + c0 + toff, lA + 4 * 2048);
            for (int dx = 0; dx < 3; ++dx) {
                const int boff = (dy * 3 + dx) * 65536 + c0;
#pragma unroll
                for (int i = 0; i < 4; ++i)
                    gl_lds16(BT + bg[i] + boff, lB + i * 2048);
                __syncthreads();
                int rowi[4];
#pragma unroll
                for (int i = 0; i < 4; ++i) rowi[i] = pb[i] + dx;
#pragma unroll
                for (int ks = 0; ks < 2; ++ks) {
                    const int qk = quad + ks * 4;
                    bf16x8 af[4], bfv[4];
#pragma unroll
                    for (int i = 0; i < 4; ++i)
                        af[i] = *(const bf16x8*)(Als + (rowi[i] << 6) +
                                                 ((qk ^ (rowi[i] & 7)) << 3));
#pragma unroll
                    for (int j = 0; j < 4; ++j)
                        bfv[j] = *(const bf16x8*)(Bls + bRow + j * 1024 +
                                                  ((qk ^ bsw) << 3));
#pragma unroll
                    for (int i = 0; i < 4; ++i)
#pragma unroll
                        for (int j = 0; j < 4; ++j)
                            acc[i][j] = __builtin_amdgcn_mfma_f32_16x16x32_bf16(
                                af[i], bfv[j], acc[i][j], 0, 0, 0);
                }
                __syncthreads();
            }
        }
    }

    // ---- epilogue: bias+relu+cvt -> wave-private swizzled T -> 16B stores
    float bv[4];
#pragma unroll
    for (int j = 0; j < 4; ++j) bv[j] = bias[n0 + wn + j * 16 + l16];
    bf16* Tw = Sh + wv * 4096;                    // 64x64 bf16, chunk-swizzled
#pragma unroll
    for (int i = 0; i < 4; ++i)
#pragma unroll
        for (int r = 0; r < 4; ++r) {
            const int row = i * 16 + quad * 4 + r;
#pragma unroll
            for (int j = 0; j < 4; ++j) {
                float v = acc[i][j][r] + bv[j];
                v = v > 0.0f ? v : 0.0f;
                const int sc = (((j * 2 + (l16 >> 3)) ^ (row & 7)) << 3) + (l16 & 7);
                Tw[row * 64 + sc] = (bf16)v;
            }
        }
    __syncthreads();
    const int rgrp = lane >> 3, cc = lane & 7;
#pragma unroll
    for (int p = 0; p < 8; ++p) {
        const int row = p * 8 + rgrp;
        bf16x8 vv = *(const bf16x8*)(Tw + row * 64 + ((cc ^ (row & 7)) << 3));
        const int ml = wm + row;
        const int y  = y0 + (ml >> lw);
        const int x  = ml & (W - 1);
        *(bf16x8*)(O + ibase + ((y + 1) * Wp + (x + 1)) * 256 + n0 + wn + cc * 8) = vv;
    }
}

// ---------------------------------------------------------------------------
// Fused prediction conv (cls 80 cols from cls-feat + box/ctr 5 cols from
// box-feat). M-tile 128; writes fp32 straight into d_out (B,5376,85).
// ---------------------------------------------------------------------------
__global__ __launch_bounds__(256) void pred_conv_kernel(
    PredTab tab, const bf16* __restrict__ BT, const float* __restrict__ bias,
    float* __restrict__ out)
{
    const int bx = blockIdx.x;
    const int l  = (bx >= tab.xend0) + (bx >= tab.xend1);
    const int start = (l == 0) ? 0 : (l == 1 ? tab.xend0 : tab.xend1);
    const int mt = bx - start;
    const int H = tab.H[l], lw = tab.lw[l], lhw = tab.lhw[l], off_l = tab.offl[l];
    const bf16* Ac = tab.inC[l];
    const bf16* Ab = tab.inB[l];

    const int W   = 1 << lw;
    const int Wp  = W + 2;
    const int HW  = 1 << lhw;
    const int tid = threadIdx.x;
    const int m_base = mt * 128;
    const int b   = m_base >> lhw;
    const int mi  = m_base & (HW - 1);
    const int y0  = mi >> lw;
    const int ibase = b * (H + 2) * Wp * 256;

    __shared__ __align__(16) bf16 Sh[(128 + 128 + 96) * 64];  // Ac|Ab|B

    const int ch8   = (((tid & 7) ^ ((tid >> 3) & 7)) << 3);
    const int rbase = tid >> 3;
    int ag[4], bg[3];
#pragma unroll
    for (int i = 0; i < 4; ++i) {
        int row = i * 32 + rbase;
        int y = y0 + (row >> lw);
        int x = row & (W - 1);
        ag[i] = ibase + (y * Wp + x) * 256 + ch8;
    }
#pragma unroll
    for (int i = 0; i < 3; ++i)
        bg[i] = (i * 32 + rbase) * 256 + ch8;

    f32x4 accC[2][5], accB[2];
#pragma unroll
    for (int i = 0; i < 2; ++i) {
#pragma unroll
        for (int j = 0; j < 5; ++j) accC[i][j] = (f32x4)(0.0f);
        accB[i] = (f32x4)(0.0f);
    }

    const int lane = tid & 63;
    const int wv   = tid >> 6;
    const int l16  = lane & 15;
    const int quad = lane >> 4;
    const int xsw  = l16 & 7;
    const int aRow = (wv * 32 + l16) * 64;
    bf16* lS = Sh + tid * 8;

    for (int kc = 0; kc < 36; ++kc) {
        const int t  = kc >> 2;
        const int dy = t / 3;
        const int dx = t - dy * 3;
        const int c0 = (kc & 3) << 6;
        const int aoff = (dy * Wp + dx) * 256 + c0;
        const int boff = t * 24576 + c0;          // t*96*256
#pragma unroll
        for (int i = 0; i < 4; ++i)
            gl_lds16(Ac + ag[i] + aoff, lS + i * 2048);
#pragma unroll
        for (int i = 0; i < 4; ++i)
            gl_lds16(Ab + ag[i] + aoff, lS + (4 + i) * 2048);
#pragma unroll
        for (int i = 0; i < 3; ++i)
            gl_lds16(BT + bg[i] + boff, lS + (8 + i) * 2048);
        __syncthreads();
#pragma unroll
        for (int ks = 0; ks < 2; ++ks) {
            const int cO = (((quad + ks * 4) ^ xsw) << 3);
            bf16x8 afc[2], afb[2], bfv[5], bfb;
#pragma unroll
            for (int i = 0; i < 2; ++i) {
                afc[i] = *(const bf16x8*)(Sh + aRow + i * 1024 + cO);
                afb[i] = *(const bf16x8*)(Sh + 8192 + aRow + i * 1024 + cO);
            }
#pragma unroll
            for (int j = 0; j < 5; ++j)
                bfv[j] = *(const bf16x8*)(Sh + 16384 + (j * 16 + l16) * 64 + cO);
            bfb = *(const bf16x8*)(Sh + 16384 + (80 + l16) * 64 + cO);
#pragma unroll
            for (int i = 0; i < 2; ++i) {
#pragma unroll
                for (int j = 0; j < 5; ++j)
                    accC[i][j] = __builtin_amdgcn_mfma_f32_16x16x32_bf16(
                        afc[i], bfv[j], accC[i][j], 0, 0, 0);
                accB[i] = __builtin_amdgcn_mfma_f32_16x16x32_bf16(
                    afb[i], bfb, accB[i], 0, 0, 0);
            }
        }
        __syncthreads();
    }

#pragma unroll
    for (int i = 0; i < 2; ++i) {
#pragma unroll
        for (int r = 0; r < 4; ++r) {
            const int ml  = wv * 32 + i * 16 + quad * 4 + r;
            const int pos = mi + ml;
            const int ob  = (b * 5376 + off_l + pos) * 85;
#pragma unroll
            for (int j = 0; j < 5; ++j)
                out[ob + j * 16 + l16] = accC[i][j][r] + bias[j * 16 + l16];
            if (l16 < 5)
                out[ob + 80 + l16] = accB[i][r] + bias[80 + l16];
        }
    }
}

// ---------------------------------------------------------------------------
// Layout transforms / init
// ---------------------------------------------------------------------------
__global__ void cast_pad_kernel(const float* __restrict__ in, bf16* __restrict__ out,
                                int H, int lw)
{
    const int c  = threadIdx.x;
    const int hw = blockIdx.x;
    const int b  = blockIdx.y;
    const int W  = 1 << lw;
    const int y  = hw >> lw;
    const int x  = hw & (W - 1);
    float v = in[((b * 256 + c) * H + y) * W + x];
    out[((b * (H + 2) + y + 1) * (W + 2) + (x + 1)) * 256 + c] = (bf16)v;
}

// zero borders of 5 contiguous padded buffers (one block = one border px)
__global__ void border_zero_kernel(bf16* base, int H, size_t bufElems, int pxPerImg)
{
    const int i   = blockIdx.x;
    const int buf = blockIdx.y;
    const int c   = threadIdx.x;
    const int img = i / pxPerImg;
    const int p   = i - img * pxPerImg;
    const int Wp  = H + 2, Hp = H + 2;
    int y, xp;
    if (p < Wp)            { y = 0;      xp = p; }
    else if (p < 2 * Wp)   { y = Hp - 1; xp = p - Wp; }
    else { int q = p - 2 * Wp; y = 1 + (q >> 1); xp = (q & 1) ? (Wp - 1) : 0; }
    base[buf * bufElems + ((size_t)(img * Hp + y) * Wp + xp) * 256 + c] = (bf16)0.0f;
}

// stem weights (S,co,ci,3,3) fp32 -> [s][t][co][ci] bf16
__global__ void prepack_stem_kernel(const float* __restrict__ w, bf16* __restrict__ o)
{
    const int ci = threadIdx.x;
    const int g  = blockIdx.x;          // (s*9+t)*256 + co
    const int co = g & 255;
    const int st = g >> 8;
    const int s  = st / 9;
    const int t  = st - s * 9;
    o[(size_t)g * 256 + ci] = (bf16)w[(((s * 256 + co) * 256 + ci) * 9) + t];
}

// pred weights -> [t][96][256]: rows 0..79 cls, 80..83 box, 84 ctr, 85..95 pad
__global__ void prepack_pred_kernel(const float* __restrict__ wc,
                                    const float* __restrict__ wb,
                                    const float* __restrict__ wr,
                                    const float* __restrict__ cb,
                                    const float* __restrict__ bb,
                                    const float* __restrict__ br,
                                    bf16* __restrict__ oT, float* __restrict__ obias)
{
    const int ci = threadIdx.x;
    const int g  = blockIdx.x;          // 0 .. 9*96-1
    const int t  = g / 96;
    const int co = g - t * 96;
    float v = 0.0f;
    if (co < 80)       v = wc[((co * 256 + ci) * 9) + t];
    else if (co < 84)  v = wb[(((co - 80) * 256 + ci) * 9) + t];
    else if (co == 84) v = wr[(ci * 9) + t];
    oT[(size_t)g * 256 + ci] = (bf16)v;
    if (g == 0 && ci < 96) {
        float bvv = 0.0f;
        if (ci < 80)       bvv = cb[ci];
        else if (ci < 84)  bvv = bb[ci - 80];
        else if (ci == 84) bvv = br[0];
        obias[ci] = bvv;
    }
}

// ---------------------------------------------------------------------------
extern "C" void kernel_launch(void* const* d_in, const int* in_sizes, int n_in,
                              void* d_out, int out_size, void* d_ws, size_t ws_size,
                              hipStream_t stream)
{
    (void)in_sizes; (void)n_in; (void)out_size;
    const float* feat[3] = {(const float*)d_in[0], (const float*)d_in[1],
                            (const float*)d_in[2]};
    const float* scw = (const float*)d_in[3];
    const float* scb = (const float*)d_in[4];
    const float* sbw = (const float*)d_in[5];
    const float* sbb = (const float*)d_in[6];
    const float* pcw = (const float*)d_in[7];
    const float* pcb = (const float*)d_in[8];
    const float* pbw = (const float*)d_in[9];
    const float* pbb = (const float*)d_in[10];
    const float* prw = (const float*)d_in[11];
    const float* prb = (const float*)d_in[12];
    float* out = (float*)d_out;

    const int Hs[3]   = {64, 32, 16};
    const int lws[3]  = {6, 5, 4};
    const int lhws[3] = {12, 10, 8};
    const int offl[3] = {0, 4096, 5120};
    const int mtiles[3] = {512, 128, 32};          // M/128 per level
    size_t bufB[3];
    for (int l = 0; l < 3; ++l)
        bufB[l] = (size_t)16 * (Hs[l] + 2) * (Hs[l] + 2) * 256 * 2;

    const size_t WSTEM = (size_t)4 * 9 * 256 * 256 * 2;
    const size_t WPRED = (size_t)9 * 96 * 256 * 2;
    const size_t FULL   = 5 * (bufB[0] + bufB[1] + bufB[2]) + 2 * WSTEM + WPRED + 384;
    const size_t SHARED = 5 * bufB[0] + 2 * WSTEM + WPRED + 384;
    if (ws_size < SHARED) return;
    const bool fused = ws_size >= FULL;

    char* ws = (char*)d_ws;
    bf16* act[3][5];
    size_t off = 0;
    if (fused) {
        for (int l = 0; l < 3; ++l)
            for (int k = 0; k < 5; ++k) { act[l][k] = (bf16*)(ws + off); off += bufB[l]; }
    } else {
        for (int k = 0; k < 5; ++k)
            for (int l = 0; l < 3; ++l) act[l][k] = (bf16*)(ws + (size_t)k * bufB[0]);
        off = 5 * bufB[0];
    }
    bf16*  wbTc = (bf16*)(ws + off); off += WSTEM;
    bf16*  wbTb = (bf16*)(ws + off); off += WSTEM;
    bf16*  pT   = (bf16*)(ws + off); off += WPRED;
    float* pB   = (float*)(ws + off);

    prepack_stem_kernel<<<dim3(9216), 256, 0, stream>>>(scw, wbTc);
    prepack_stem_kernel<<<dim3(9216), 256, 0, stream>>>(sbw, wbTb);
    prepack_pred_kernel<<<dim3(9 * 96), 256, 0, stream>>>(pcw, pbw, prw, pcb, pbb, prb,
                                                          pT, pB);

    auto launch_level_init = [&](int l) {
        const int H = Hs[l];
        const int px = 2 * (H + 2) + 2 * H;
        border_zero_kernel<<<dim3(16 * px, 5), 256, 0, stream>>>(
            act[l][0], H, bufB[l] / 2, px);
        cast_pad_kernel<<<dim3(H * H, 16), 256, 0, stream>>>(feat[l], act[l][0], H, lws[l]);
    };

    auto make_stem_tab = [&](int s, int nlev, const int* levs) {
        StemTab tb{};
        for (int i = 0; i < nlev; ++i) {
            int l = levs[i];
            tb.inC[i]  = (s == 0) ? act[l][0] : ((s & 1) ? act[l][1] : act[l][2]);
            tb.inB[i]  = (s == 0) ? act[l][0] : ((s & 1) ? act[l][3] : act[l][4]);
            tb.outC[i] = (s & 1) ? act[l][2] : act[l][1];
            tb.outB[i] = (s & 1) ? act[l][4] : act[l][3];
            tb.H[i] = Hs[l]; tb.lw[i] = lws[l]; tb.lhw[i] = lhws[l];
        }
        return tb;
    };

    if (fused) {
        for (int l = 0; l < 3; ++l) launch_level_init(l);
        const int levs[3] = {0, 1, 2};
        const int tx0 = mtiles[0] * 2, tx1 = mtiles[1] * 2, tx2 = mtiles[2] * 2;
        for (int s = 0; s < 4; ++s) {
            StemTab tb = make_stem_tab(s, 3, levs);
            tb.xend0 = tx0; tb.xend1 = tx0 + tx1;
            stem_conv_kernel<<<dim3(tx0 + tx1 + tx2, 1, 2), 256, 0, stream>>>(
                tb, wbTc + (size_t)s * 589824, wbTb + (size_t)s * 589824,
                scb + s * 256, sbb + s * 256);
        }
        PredTab pt{};
        for (int l = 0; l < 3; ++l) {
            pt.inC[l] = act[l][2]; pt.inB[l] = act[l][4];
            pt.H[l] = Hs[l]; pt.lw[l] = lws[l]; pt.lhw[l] = lhws[l]; pt.offl[l] = offl[l];
        }
        pt.xend0 = mtiles[0]; pt.xend1 = mtiles[0] + mtiles[1];
        pred_conv_kernel<<<dim3(mtiles[0] + mtiles[1] + mtiles[2]), 256, 0, stream>>>(
            pt, pT, pB, out);
    } else {
        for (int l = 0; l < 3; ++l) {
            launch_level_init(l);
            const int levs[1] = {l};
            const int tiles = mtiles[l] * 2;
            for (int s = 0; s < 4; ++s) {
                StemTab tb = make_stem_tab(s, 1, levs);
                tb.xend0 = tiles; tb.xend1 = tiles;
                stem_conv_kernel<<<dim3(tiles, 1, 2), 256, 0, stream>>>(
                    tb, wbTc + (size_t)s * 589824, wbTb + (size_t)s * 589824,
                    scb + s * 256, sbb + s * 256);
            }
            PredTab pt{};
            pt.inC[0] = act[l][2]; pt.inB[0] = act[l][4];
            pt.H[0] = Hs[l]; pt.lw[0] = lws[l]; pt.lhw[0] = lhws[l]; pt.offl[0] = offl[l];
            pt.xend0 = mtiles[l]; pt.xend1 = mtiles[l];
            pred_conv_kernel<<<dim3(mtiles[l]), 256, 0, stream>>>(pt, pT, pB, out);
        }
    }
}